// Round 1
// baseline (733.402 us; speedup 1.0000x reference)
//
#include <hip/hip_runtime.h>
#include <hip/hip_bf16.h>

typedef __bf16 bf16x8 __attribute__((ext_vector_type(8)));
typedef float f32x4 __attribute__((ext_vector_type(4)));
typedef unsigned short u16;

#define DEV __device__ __forceinline__

DEV u16 f2b(float f) {
  __hip_bfloat16 h = __float2bfloat16(f);
  return __builtin_bit_cast(u16, h);
}

// ---------------------------------------------------------------------------
// Weight convert+transpose: W (1024x1024 f32, row=k) -> Wt (1024x1024 bf16, row=n)
// ---------------------------------------------------------------------------
__global__ __launch_bounds__(256) void wcvt_kernel(const float* __restrict__ W,
                                                   u16* __restrict__ Wt) {
  __shared__ u16 ls[64 * 80];
  const int bn = (blockIdx.x & 15) << 6;
  const int bk = (blockIdx.x >> 4) << 6;
  const int t = threadIdx.x;
#pragma unroll
  for (int rr = 0; rr < 4; ++rr) {
    const int r = (t >> 4) + (rr << 4);   // k-local
    const int cc = (t & 15) << 2;         // n-local
    const float4 v = *reinterpret_cast<const float4*>(&W[(size_t)(bk + r) * 1024 + bn + cc]);
    ls[(cc + 0) * 80 + r] = f2b(v.x);
    ls[(cc + 1) * 80 + r] = f2b(v.y);
    ls[(cc + 2) * 80 + r] = f2b(v.z);
    ls[(cc + 3) * 80 + r] = f2b(v.w);
  }
  __syncthreads();
#pragma unroll
  for (int it = 0; it < 2; ++it) {
    const int idx = t + (it << 8);
    const int n = idx >> 3, c8 = idx & 7;
    const uint4 o = *reinterpret_cast<const uint4*>(&ls[n * 80 + (c8 << 3)]);
    *reinterpret_cast<uint4*>(&Wt[(size_t)(bn + n) * 1024 + bk + (c8 << 3)]) = o;
  }
}

// ---------------------------------------------------------------------------
// GEMM: C(M,N) = A(M,K) @ Bt(N,K)^T + bias.  128x128 tile, BK=64, 4 waves.
// A is f32 (converted to bf16 during staging) or bf16; out bf16 or f32.
// LDS XOR-swizzled (16B slot ^ row&7) -> conflict-free b128 frag reads.
// ---------------------------------------------------------------------------
template <int A_F32, int OUT_F32>
__global__ __launch_bounds__(256, 2) void gemm_kernel(
    const void* __restrict__ Ap, const u16* __restrict__ Bt,
    const float* __restrict__ bias, void* __restrict__ Cp,
    const int M, const int N, const int K) {
  __shared__ u16 As[128 * 64];
  __shared__ u16 Bs[128 * 64];
  const int tid = threadIdx.x;
  const int lane = tid & 63;
  const int w = tid >> 6;
  const int c = lane & 15;
  const int g = lane >> 4;
  const int ntN = N >> 7;
  const int bm = (int)blockIdx.x / ntN;
  const int bn = (int)blockIdx.x - bm * ntN;
  const int m0 = bm << 7, n0 = bn << 7;
  const float* __restrict__ Af = (const float*)Ap;
  const u16* __restrict__ Ab = (const u16*)Ap;

  const int srow = tid >> 3, sc8 = tid & 7;        // staging coords
  const int swslot = sc8 ^ (srow & 7);             // swizzled 16B slot (row&7 invariant over +32)

  float4 fA0[4], fA1[4];
  uint4 uA[4], uB[4];

  auto LOAD = [&](int kt) {
    const int k0 = kt << 6;
#pragma unroll
    for (int i = 0; i < 4; ++i) {
      const int row = srow + (i << 5);
      if (A_F32) {
        const float* s = Af + (size_t)(m0 + row) * K + k0 + (sc8 << 3);
        fA0[i] = *reinterpret_cast<const float4*>(s);
        fA1[i] = *reinterpret_cast<const float4*>(s + 4);
      } else {
        uA[i] = *reinterpret_cast<const uint4*>(Ab + (size_t)(m0 + row) * K + k0 + (sc8 << 3));
      }
      uB[i] = *reinterpret_cast<const uint4*>(Bt + (size_t)(n0 + row) * K + k0 + (sc8 << 3));
    }
  };
  auto WRITE = [&]() {
#pragma unroll
    for (int i = 0; i < 4; ++i) {
      const int row = srow + (i << 5);
      const int off = (row << 6) + (swslot << 3);
      if (A_F32) {
        bf16x8 v;
        v[0] = (__bf16)fA0[i].x; v[1] = (__bf16)fA0[i].y;
        v[2] = (__bf16)fA0[i].z; v[3] = (__bf16)fA0[i].w;
        v[4] = (__bf16)fA1[i].x; v[5] = (__bf16)fA1[i].y;
        v[6] = (__bf16)fA1[i].z; v[7] = (__bf16)fA1[i].w;
        *reinterpret_cast<bf16x8*>(&As[off]) = v;
      } else {
        *reinterpret_cast<uint4*>(&As[off]) = uA[i];
      }
      *reinterpret_cast<uint4*>(&Bs[off]) = uB[i];
    }
  };

  f32x4 acc[4][4];
#pragma unroll
  for (int mi = 0; mi < 4; ++mi)
#pragma unroll
    for (int ni = 0; ni < 4; ++ni) acc[mi][ni] = f32x4{0.f, 0.f, 0.f, 0.f};

  const int wm = (w >> 1) << 6, wn = (w & 1) << 6;
  const int NT = K >> 6;
  LOAD(0);
  for (int kt = 0; kt < NT; ++kt) {
    WRITE();
    if (kt + 1 < NT) LOAD(kt + 1);   // prefetch stays in flight across barrier (no vmcnt drain)
    asm volatile("s_waitcnt lgkmcnt(0)" ::: "memory");
    __builtin_amdgcn_s_barrier();
    bf16x8 af[4][2], bfr[4][2];
#pragma unroll
    for (int mi = 0; mi < 4; ++mi) {
      const int row = wm + (mi << 4) + c;
#pragma unroll
      for (int kk = 0; kk < 2; ++kk) {
        const int slot = ((kk << 2) + g) ^ (row & 7);
        af[mi][kk] = *reinterpret_cast<const bf16x8*>(&As[(row << 6) + (slot << 3)]);
      }
    }
#pragma unroll
    for (int ni = 0; ni < 4; ++ni) {
      const int row = wn + (ni << 4) + c;
#pragma unroll
      for (int kk = 0; kk < 2; ++kk) {
        const int slot = ((kk << 2) + g) ^ (row & 7);
        bfr[ni][kk] = *reinterpret_cast<const bf16x8*>(&Bs[(row << 6) + (slot << 3)]);
      }
    }
#pragma unroll
    for (int mi = 0; mi < 4; ++mi)
#pragma unroll
      for (int ni = 0; ni < 4; ++ni) {
        acc[mi][ni] = __builtin_amdgcn_mfma_f32_16x16x32_bf16(af[mi][0], bfr[ni][0], acc[mi][ni], 0, 0, 0);
        acc[mi][ni] = __builtin_amdgcn_mfma_f32_16x16x32_bf16(af[mi][1], bfr[ni][1], acc[mi][ni], 0, 0, 0);
      }
    __builtin_amdgcn_s_barrier();
  }

  // epilogue: C layout col = lane&15, row = 4*(lane>>4)+r
#pragma unroll
  for (int ni = 0; ni < 4; ++ni) {
    const int ncol = n0 + wn + (ni << 4) + c;
    const float bv = bias[ncol];
#pragma unroll
    for (int mi = 0; mi < 4; ++mi) {
      const int mrow = m0 + wm + (mi << 4) + (g << 2);
#pragma unroll
      for (int r = 0; r < 4; ++r) {
        const float v = acc[mi][ni][r] + bv;
        if (OUT_F32)
          ((float*)Cp)[(size_t)(mrow + r) * N + ncol] = v;
        else
          ((u16*)Cp)[(size_t)(mrow + r) * N + ncol] = f2b(v);
      }
    }
  }
}

// ---------------------------------------------------------------------------
// Streaming attention. 1 block = (b, chunk, head), 2 waves split q-tiles.
// chunk 0: 128 q x 128 k; chunk c>=1: 96 q (local 32..127) x 160 k (c*128-32..).
// Q/K frags straight from global; V^T in swizzled LDS; P bounced via LDS.
// ---------------------------------------------------------------------------
#define VT_STR 200  // elems per d-row of V^T (25 x 16B units; swizzle needs <=24)
#define PS_STR 168

template <int NKT>
DEV void attn_process(const u16* __restrict__ Qg, const u16* __restrict__ Kg,
                      u16* __restrict__ Og, const u16* Vt, u16* Pw,
                      int b, int h, int qpos0, int kpos0, int obase, int nqt,
                      int wv, int lane) {
  const int c = lane & 15, g = lane >> 4;
  constexpr float SC = 0.18033688f;  // (1/sqrt(64)) * log2(e)
  for (int qt = wv; qt < nqt; qt += 2) {
    bf16x8 aq[2];
#pragma unroll
    for (int kk = 0; kk < 2; ++kk)
      aq[kk] = *reinterpret_cast<const bf16x8*>(
          Qg + ((size_t)(b * 4096 + qpos0 + (qt << 4) + c)) * 1024 + h * 64 + (kk << 5) + (g << 3));

    f32x4 sacc[NKT];
#pragma unroll
    for (int i = 0; i < NKT; ++i) sacc[i] = f32x4{0.f, 0.f, 0.f, 0.f};
#pragma unroll
    for (int kt = 0; kt < NKT; ++kt) {
#pragma unroll
      for (int kk = 0; kk < 2; ++kk) {
        const bf16x8 bk = *reinterpret_cast<const bf16x8*>(
            Kg + ((size_t)(b * 4096 + kpos0 + (kt << 4) + c)) * 1024 + h * 64 + (kk << 5) + (g << 3));
        sacc[kt] = __builtin_amdgcn_mfma_f32_16x16x32_bf16(aq[kk], bk, sacc[kt], 0, 0, 0);
      }
    }

    // online-free softmax: lane holds rows q=4g+r, cols k=16*kt+c
    float m[4], sum[4], rs[4];
#pragma unroll
    for (int r = 0; r < 4; ++r) m[r] = -1e30f;
#pragma unroll
    for (int kt = 0; kt < NKT; ++kt)
#pragma unroll
      for (int r = 0; r < 4; ++r) m[r] = fmaxf(m[r], sacc[kt][r]);
#pragma unroll
    for (int msk = 1; msk < 16; msk <<= 1)
#pragma unroll
      for (int r = 0; r < 4; ++r) m[r] = fmaxf(m[r], __shfl_xor(m[r], msk, 64));
#pragma unroll
    for (int r = 0; r < 4; ++r) { m[r] *= SC; sum[r] = 0.f; }
#pragma unroll
    for (int kt = 0; kt < NKT; ++kt)
#pragma unroll
      for (int r = 0; r < 4; ++r) {
        const float p = exp2f(sacc[kt][r] * SC - m[r]);
        sum[r] += p;
        Pw[((g << 2) + r) * PS_STR + (kt << 4) + c] = f2b(p);
      }
#pragma unroll
    for (int msk = 1; msk < 16; msk <<= 1)
#pragma unroll
      for (int r = 0; r < 4; ++r) sum[r] += __shfl_xor(sum[r], msk, 64);
#pragma unroll
    for (int r = 0; r < 4; ++r) rs[r] = 1.f / sum[r];

    asm volatile("s_waitcnt lgkmcnt(0)" ::: "memory");
    __builtin_amdgcn_sched_barrier(0);

    // PV: A = P (row=lane&15 from LDS), B = V^T rows (swizzled), O rows = 4g+r
    f32x4 oacc[4];
#pragma unroll
    for (int nd = 0; nd < 4; ++nd) oacc[nd] = f32x4{0.f, 0.f, 0.f, 0.f};
#pragma unroll
    for (int u = 0; u < NKT / 2; ++u) {
      const bf16x8 pa = *reinterpret_cast<const bf16x8*>(&Pw[c * PS_STR + (u << 5) + (g << 3)]);
#pragma unroll
      for (int nd = 0; nd < 4; ++nd) {
        const int d = (nd << 4) + c;
        const int a = (u << 2) + g;
        const int us = (a & 24) | ((a ^ (d >> 3)) & 7);
        const bf16x8 vbf = *reinterpret_cast<const bf16x8*>(&Vt[d * VT_STR + (us << 3)]);
        oacc[nd] = __builtin_amdgcn_mfma_f32_16x16x32_bf16(pa, vbf, oacc[nd], 0, 0, 0);
      }
    }

    const int orow0 = b * 3104 + obase + (qt << 4) + (g << 2);
#pragma unroll
    for (int nd = 0; nd < 4; ++nd)
#pragma unroll
      for (int r = 0; r < 4; ++r)
        Og[(size_t)(orow0 + r) * 1024 + h * 64 + (nd << 4) + c] = f2b(oacc[nd][r] * rs[r]);
  }
}

__global__ __launch_bounds__(128) void attn_kernel(
    const u16* __restrict__ Qg, const u16* __restrict__ Kg,
    const u16* __restrict__ Vg, u16* __restrict__ Og) {
  __shared__ u16 Vt[64 * VT_STR];
  __shared__ u16 Ps[2 * 16 * PS_STR];
  const int bid = blockIdx.x;
  const int b = bid >> 9;
  const int ch = (bid >> 4) & 31;
  const int h = bid & 15;
  const int t = threadIdx.x, wv = t >> 6, lane = t & 63;
  int qpos0, kpos0, obase, nk;
  if (ch == 0) { qpos0 = 0; kpos0 = 0; obase = 0; nk = 128; }
  else { qpos0 = (ch << 7) + 32; kpos0 = (ch << 7) - 32; obase = 128 + (ch - 1) * 96; nk = 160; }

  // stage V^T: Vt[d][k], swizzled 16B unit us = (k8&24)|((k8^(d>>3))&7)
  const size_t vbase = ((size_t)(b * 4096 + kpos0)) * 1024 + h * 64;
  for (int ch8 = t; ch8 < nk * 8; ch8 += 128) {
    const int k = ch8 >> 3, c8 = ch8 & 7;
    const uint4 v = *reinterpret_cast<const uint4*>(Vg + vbase + (size_t)k * 1024 + (c8 << 3));
    const unsigned vv[4] = {v.x, v.y, v.z, v.w};
    const int k8 = k >> 3;
    const int us = (k8 & 24) | ((k8 ^ c8) & 7);  // d>>3 == c8 for d = 8*c8+j
    const int base = (us << 3) + (k & 7);
#pragma unroll
    for (int j = 0; j < 8; ++j) {
      const u16 e = (u16)(vv[j >> 1] >> ((j & 1) << 4));
      Vt[((c8 << 3) + j) * VT_STR + base] = e;
    }
  }
  __syncthreads();

  u16* Pw = Ps + wv * (16 * PS_STR);
  if (ch == 0)
    attn_process<8>(Qg, Kg, Og, Vt, Pw, b, h, qpos0, kpos0, obase, 8, wv, lane);
  else
    attn_process<10>(Qg, Kg, Og, Vt, Pw, b, h, qpos0, kpos0, obase, 6, wv, lane);
}

// ---------------------------------------------------------------------------
extern "C" void kernel_launch(void* const* d_in, const int* in_sizes, int n_in,
                              void* d_out, int out_size, void* d_ws, size_t ws_size,
                              hipStream_t stream) {
  (void)in_sizes; (void)n_in; (void)out_size;
  const float* query  = (const float*)d_in[0];
  const float* key_in = (const float*)d_in[1];
  const float* value  = (const float*)d_in[2];
  const float* Wq = (const float*)d_in[3];
  const float* bq = (const float*)d_in[4];
  const float* Wk = (const float*)d_in[5];
  const float* bk = (const float*)d_in[6];
  const float* Wv = (const float*)d_in[7];
  const float* bv = (const float*)d_in[8];
  const float* Wo = (const float*)d_in[9];
  const float* bo = (const float*)d_in[10];

  char* ws = (char*)d_ws;
  const size_t WSZ = 2097152;    // 1024*1024*2
  const size_t ASZ = 33554432;   // 16384*1024*2
  u16* WtQ = (u16*)(ws + 0 * WSZ);
  u16* WtK = (u16*)(ws + 1 * WSZ);
  u16* WtV = (u16*)(ws + 2 * WSZ);
  u16* WtO = (u16*)(ws + 3 * WSZ);
  u16* qb = (u16*)(ws + 4 * WSZ);
  u16* kb = (u16*)(ws + 4 * WSZ + 1 * ASZ);
  u16* vb = (u16*)(ws + 4 * WSZ + 2 * ASZ);
  u16* ao = (u16*)(ws + 4 * WSZ + 3 * ASZ);
  if (ws_size < (size_t)134479872) return;  // 8MB weights + 96MB qkv + 24.25MB attn-out

  wcvt_kernel<<<256, 256, 0, stream>>>(Wq, WtQ);
  wcvt_kernel<<<256, 256, 0, stream>>>(Wk, WtK);
  wcvt_kernel<<<256, 256, 0, stream>>>(Wv, WtV);
  wcvt_kernel<<<256, 256, 0, stream>>>(Wo, WtO);
  gemm_kernel<1, 0><<<1024, 256, 0, stream>>>(query,  WtQ, bq, qb, 16384, 1024, 1024);
  gemm_kernel<1, 0><<<1024, 256, 0, stream>>>(key_in, WtK, bk, kb, 16384, 1024, 1024);
  gemm_kernel<1, 0><<<1024, 256, 0, stream>>>(value,  WtV, bv, vb, 16384, 1024, 1024);
  attn_kernel<<<2048, 128, 0, stream>>>(qb, kb, vb, ao);
  gemm_kernel<0, 1><<<776, 256, 0, stream>>>(ao, WtO, bo, (float*)d_out, 12416, 1024, 1024);
}

// Round 2
// 346.581 us; speedup vs baseline: 2.1161x; 2.1161x over previous
//
#include <hip/hip_runtime.h>
#include <hip/hip_bf16.h>

typedef __bf16 bf16x8 __attribute__((ext_vector_type(8)));
typedef float f32x4 __attribute__((ext_vector_type(4)));
typedef unsigned short u16;

#define DEV __device__ __forceinline__

DEV u16 f2b(float f) {
  __hip_bfloat16 h = __float2bfloat16(f);
  return __builtin_bit_cast(u16, h);
}

DEV void gl_lds16(const u16* g, u16* l) {
  __builtin_amdgcn_global_load_lds(
      (const __attribute__((address_space(1))) void*)g,
      (__attribute__((address_space(3))) void*)l, 16, 0, 0);
}

// ---------------------------------------------------------------------------
// f32 -> bf16 elementwise convert (memory-bound, vectorized 8 elems/thread/iter)
// ---------------------------------------------------------------------------
__global__ __launch_bounds__(256) void cvt_kernel(const float* __restrict__ in,
                                                  u16* __restrict__ out, int n8) {
  const int stride = gridDim.x * 256;
  for (int i = blockIdx.x * 256 + threadIdx.x; i < n8; i += stride) {
    const float4 a = *reinterpret_cast<const float4*>(in + (size_t)i * 8);
    const float4 b = *reinterpret_cast<const float4*>(in + (size_t)i * 8 + 4);
    union { u16 s[8]; uint4 u; } o;
    o.s[0] = f2b(a.x); o.s[1] = f2b(a.y); o.s[2] = f2b(a.z); o.s[3] = f2b(a.w);
    o.s[4] = f2b(b.x); o.s[5] = f2b(b.y); o.s[6] = f2b(b.z); o.s[7] = f2b(b.w);
    *reinterpret_cast<uint4*>(out + (size_t)i * 8) = o.u;
  }
}

// ---------------------------------------------------------------------------
// Weight convert+transpose: W (1024x1024 f32, row=k) -> Wt (1024x1024 bf16, row=n)
// ---------------------------------------------------------------------------
__global__ __launch_bounds__(256) void wcvt_kernel(const float* __restrict__ W,
                                                   u16* __restrict__ Wt) {
  __shared__ u16 ls[64 * 80];
  const int bn = (blockIdx.x & 15) << 6;
  const int bk = (blockIdx.x >> 4) << 6;
  const int t = threadIdx.x;
#pragma unroll
  for (int rr = 0; rr < 4; ++rr) {
    const int r = (t >> 4) + (rr << 4);   // k-local
    const int cc = (t & 15) << 2;         // n-local
    const float4 v = *reinterpret_cast<const float4*>(&W[(size_t)(bk + r) * 1024 + bn + cc]);
    ls[(cc + 0) * 80 + r] = f2b(v.x);
    ls[(cc + 1) * 80 + r] = f2b(v.y);
    ls[(cc + 2) * 80 + r] = f2b(v.z);
    ls[(cc + 3) * 80 + r] = f2b(v.w);
  }
  __syncthreads();
#pragma unroll
  for (int it = 0; it < 2; ++it) {
    const int idx = t + (it << 8);
    const int n = idx >> 3, c8 = idx & 7;
    const uint4 o = *reinterpret_cast<const uint4*>(&ls[n * 80 + (c8 << 3)]);
    *reinterpret_cast<uint4*>(&Wt[(size_t)(bn + n) * 1024 + bk + (c8 << 3)]) = o;
  }
}

// ---------------------------------------------------------------------------
// GEMM (m97 structure): C(M,N) = A(M,K)@Bt(N,K)^T + bias. All bf16 in.
// 128x128 tile, BK=64, 4 waves, global_load_lds width 16, linear LDS,
// plain __syncthreads (vmcnt drain) x2 per k-step. XCD-swizzled grid.
// Epilogue bounces C through LDS for coalesced 16B/lane stores.
// ---------------------------------------------------------------------------
template <int OUT_F32>
__global__ __launch_bounds__(256) void gemm_bt(
    const u16* __restrict__ A, const u16* __restrict__ Bt,
    const float* __restrict__ bias, void* __restrict__ Cp,
    const int M, const int N, const int K) {
  __shared__ u16 smem[128 * 128];           // As = [0,8192), Bs = [8192,16384)
  u16* As = smem;
  u16* Bs = smem + 128 * 64;
  const int tid = threadIdx.x;
  const int lane = tid & 63;
  const int w = tid >> 6;
  const int c = lane & 15;
  const int g = lane >> 4;

  // XCD-aware bijective swizzle (gridDim.x % 8 == 0 guaranteed by launcher)
  const int cpx = (int)gridDim.x >> 3;
  const int bid = ((int)blockIdx.x & 7) * cpx + ((int)blockIdx.x >> 3);
  const int ntN = N >> 7;
  const int bm = bid / ntN;
  const int bn = bid - bm * ntN;
  const int m0 = bm << 7, n0 = bn << 7;

  const int rl = lane >> 3;            // row within 8-row staging group
  const int cl = (lane & 7) << 3;      // elem offset within row

  f32x4 acc[4][4];
#pragma unroll
  for (int mi = 0; mi < 4; ++mi)
#pragma unroll
    for (int ni = 0; ni < 4; ++ni) acc[mi][ni] = f32x4{0.f, 0.f, 0.f, 0.f};

  const int wm = (w >> 1) << 6, wn = (w & 1) << 6;
  const int NT = K >> 6;

  for (int kt = 0; kt < NT; ++kt) {
    const int k0 = kt << 6;
    // stage: each wave moves 32 A-rows + 32 B-rows, 1024B per call
#pragma unroll
    for (int j = 0; j < 4; ++j) {
      const int r8 = (w << 5) + (j << 3);
      gl_lds16(A  + (size_t)(m0 + r8 + rl) * K + k0 + cl, &As[r8 << 6]);
      gl_lds16(Bt + (size_t)(n0 + r8 + rl) * K + k0 + cl, &Bs[r8 << 6]);
    }
    __syncthreads();   // drains vmcnt(0): LDS tile complete

    bf16x8 af[4][2], bfr[4][2];
#pragma unroll
    for (int mi = 0; mi < 4; ++mi) {
      const int row = wm + (mi << 4) + c;
#pragma unroll
      for (int kk = 0; kk < 2; ++kk)
        af[mi][kk] = *reinterpret_cast<const bf16x8*>(&As[(row << 6) + (kk << 5) + (g << 3)]);
    }
#pragma unroll
    for (int ni = 0; ni < 4; ++ni) {
      const int row = wn + (ni << 4) + c;
#pragma unroll
      for (int kk = 0; kk < 2; ++kk)
        bfr[ni][kk] = *reinterpret_cast<const bf16x8*>(&Bs[(row << 6) + (kk << 5) + (g << 3)]);
    }
#pragma unroll
    for (int mi = 0; mi < 4; ++mi)
#pragma unroll
      for (int ni = 0; ni < 4; ++ni) {
        acc[mi][ni] = __builtin_amdgcn_mfma_f32_16x16x32_bf16(af[mi][0], bfr[ni][0], acc[mi][ni], 0, 0, 0);
        acc[mi][ni] = __builtin_amdgcn_mfma_f32_16x16x32_bf16(af[mi][1], bfr[ni][1], acc[mi][ni], 0, 0, 0);
      }
    __syncthreads();   // protect LDS before next stage overwrites
  }

  // ---- epilogue: coalesced stores via LDS bounce ----
  if (!OUT_F32) {
    u16* Cb = (u16*)Cp;
#pragma unroll
    for (int ni = 0; ni < 4; ++ni) {
      const float bv = bias[n0 + wn + (ni << 4) + c];
#pragma unroll
      for (int mi = 0; mi < 4; ++mi)
#pragma unroll
        for (int r = 0; r < 4; ++r)
          smem[(wm + (mi << 4) + (g << 2) + r) * 128 + wn + (ni << 4) + c] =
              f2b(acc[mi][ni][r] + bv);
    }
    __syncthreads();
#pragma unroll
    for (int i = 0; i < 8; ++i) {
      const int u = (i << 8) + tid;
      const int row = u >> 4, slot = u & 15;
      const uint4 v = *reinterpret_cast<const uint4*>(&smem[(row << 7) + (slot << 3)]);
      *reinterpret_cast<uint4*>(&Cb[(size_t)(m0 + row) * N + n0 + (slot << 3)]) = v;
    }
  } else {
    float* Cf = (float*)Cp;
    float* fs = (float*)smem;   // 32KB = 64 rows x 128 f32
#pragma unroll
    for (int half = 0; half < 2; ++half) {
      if ((w >> 1) == half) {
#pragma unroll
        for (int ni = 0; ni < 4; ++ni) {
          const float bv = bias[n0 + wn + (ni << 4) + c];
#pragma unroll
          for (int mi = 0; mi < 4; ++mi)
#pragma unroll
            for (int r = 0; r < 4; ++r)
              fs[((mi << 4) + (g << 2) + r) * 128 + wn + (ni << 4) + c] =
                  acc[mi][ni][r] + bv;
        }
      }
      __syncthreads();
#pragma unroll
      for (int i = 0; i < 8; ++i) {
        const int u = (i << 8) + tid;
        const int row = u >> 5, slot = u & 31;
        const float4 v = *reinterpret_cast<const float4*>(&fs[(row << 7) + (slot << 2)]);
        *reinterpret_cast<float4*>(&Cf[(size_t)(m0 + (half << 6) + row) * N + n0 + (slot << 2)]) = v;
      }
      __syncthreads();
    }
  }
}

// ---------------------------------------------------------------------------
// Streaming attention. 1 block = (b, chunk, head), 2 waves split q-tiles.
// chunk 0: 128 q x 128 k; chunk c>=1: 96 q (local 32..127) x 160 k (c*128-32..).
// Q/K frags straight from global; V^T in swizzled LDS; P bounced via LDS.
// ---------------------------------------------------------------------------
#define VT_STR 200  // elems per d-row of V^T (25 x 16B units; swizzle needs <=24)
#define PS_STR 168

template <int NKT>
DEV void attn_process(const u16* __restrict__ Qg, const u16* __restrict__ Kg,
                      u16* __restrict__ Og, const u16* Vt, u16* Pw,
                      int b, int h, int qpos0, int kpos0, int obase, int nqt,
                      int wv, int lane) {
  const int c = lane & 15, g = lane >> 4;
  constexpr float SC = 0.18033688f;  // (1/sqrt(64)) * log2(e)
  for (int qt = wv; qt < nqt; qt += 2) {
    bf16x8 aq[2];
#pragma unroll
    for (int kk = 0; kk < 2; ++kk)
      aq[kk] = *reinterpret_cast<const bf16x8*>(
          Qg + ((size_t)(b * 4096 + qpos0 + (qt << 4) + c)) * 1024 + h * 64 + (kk << 5) + (g << 3));

    f32x4 sacc[NKT];
#pragma unroll
    for (int i = 0; i < NKT; ++i) sacc[i] = f32x4{0.f, 0.f, 0.f, 0.f};
#pragma unroll
    for (int kt = 0; kt < NKT; ++kt) {
#pragma unroll
      for (int kk = 0; kk < 2; ++kk) {
        const bf16x8 bk = *reinterpret_cast<const bf16x8*>(
            Kg + ((size_t)(b * 4096 + kpos0 + (kt << 4) + c)) * 1024 + h * 64 + (kk << 5) + (g << 3));
        sacc[kt] = __builtin_amdgcn_mfma_f32_16x16x32_bf16(aq[kk], bk, sacc[kt], 0, 0, 0);
      }
    }

    float m[4], sum[4], rs[4];
#pragma unroll
    for (int r = 0; r < 4; ++r) m[r] = -1e30f;
#pragma unroll
    for (int kt = 0; kt < NKT; ++kt)
#pragma unroll
      for (int r = 0; r < 4; ++r) m[r] = fmaxf(m[r], sacc[kt][r]);
#pragma unroll
    for (int msk = 1; msk < 16; msk <<= 1)
#pragma unroll
      for (int r = 0; r < 4; ++r) m[r] = fmaxf(m[r], __shfl_xor(m[r], msk, 64));
#pragma unroll
    for (int r = 0; r < 4; ++r) { m[r] *= SC; sum[r] = 0.f; }
#pragma unroll
    for (int kt = 0; kt < NKT; ++kt)
#pragma unroll
      for (int r = 0; r < 4; ++r) {
        const float p = exp2f(sacc[kt][r] * SC - m[r]);
        sum[r] += p;
        Pw[((g << 2) + r) * PS_STR + (kt << 4) + c] = f2b(p);
      }
#pragma unroll
    for (int msk = 1; msk < 16; msk <<= 1)
#pragma unroll
      for (int r = 0; r < 4; ++r) sum[r] += __shfl_xor(sum[r], msk, 64);
#pragma unroll
    for (int r = 0; r < 4; ++r) rs[r] = 1.f / sum[r];

    asm volatile("s_waitcnt lgkmcnt(0)" ::: "memory");
    __builtin_amdgcn_sched_barrier(0);

    f32x4 oacc[4];
#pragma unroll
    for (int nd = 0; nd < 4; ++nd) oacc[nd] = f32x4{0.f, 0.f, 0.f, 0.f};
#pragma unroll
    for (int u = 0; u < NKT / 2; ++u) {
      const bf16x8 pa = *reinterpret_cast<const bf16x8*>(&Pw[c * PS_STR + (u << 5) + (g << 3)]);
#pragma unroll
      for (int nd = 0; nd < 4; ++nd) {
        const int d = (nd << 4) + c;
        const int a = (u << 2) + g;
        const int us = (a & 24) | ((a ^ (d >> 3)) & 7);
        const bf16x8 vbf = *reinterpret_cast<const bf16x8*>(&Vt[d * VT_STR + (us << 3)]);
        oacc[nd] = __builtin_amdgcn_mfma_f32_16x16x32_bf16(pa, vbf, oacc[nd], 0, 0, 0);
      }
    }

    const int orow0 = b * 3104 + obase + (qt << 4) + (g << 2);
#pragma unroll
    for (int nd = 0; nd < 4; ++nd)
#pragma unroll
      for (int r = 0; r < 4; ++r)
        Og[(size_t)(orow0 + r) * 1024 + h * 64 + (nd << 4) + c] = f2b(oacc[nd][r] * rs[r]);
  }
}

__global__ __launch_bounds__(128) void attn_kernel(
    const u16* __restrict__ Qg, const u16* __restrict__ Kg,
    const u16* __restrict__ Vg, u16* __restrict__ Og) {
  __shared__ u16 Vt[64 * VT_STR];
  __shared__ u16 Ps[2 * 16 * PS_STR];
  const int bid = blockIdx.x;
  const int b = bid >> 9;
  const int ch = (bid >> 4) & 31;
  const int h = bid & 15;
  const int t = threadIdx.x, wv = t >> 6, lane = t & 63;
  int qpos0, kpos0, obase, nk;
  if (ch == 0) { qpos0 = 0; kpos0 = 0; obase = 0; nk = 128; }
  else { qpos0 = (ch << 7) + 32; kpos0 = (ch << 7) - 32; obase = 128 + (ch - 1) * 96; nk = 160; }

  const size_t vbase = ((size_t)(b * 4096 + kpos0)) * 1024 + h * 64;
  for (int ch8 = t; ch8 < nk * 8; ch8 += 128) {
    const int k = ch8 >> 3, c8 = ch8 & 7;
    const uint4 v = *reinterpret_cast<const uint4*>(Vg + vbase + (size_t)k * 1024 + (c8 << 3));
    const unsigned vv[4] = {v.x, v.y, v.z, v.w};
    const int k8 = k >> 3;
    const int us = (k8 & 24) | ((k8 ^ c8) & 7);
    const int base = (us << 3) + (k & 7);
#pragma unroll
    for (int j = 0; j < 8; ++j) {
      const u16 e = (u16)(vv[j >> 1] >> ((j & 1) << 4));
      Vt[((c8 << 3) + j) * VT_STR + base] = e;
    }
  }
  __syncthreads();

  u16* Pw = Ps + wv * (16 * PS_STR);
  if (ch == 0)
    attn_process<8>(Qg, Kg, Og, Vt, Pw, b, h, qpos0, kpos0, obase, 8, wv, lane);
  else
    attn_process<10>(Qg, Kg, Og, Vt, Pw, b, h, qpos0, kpos0, obase, 6, wv, lane);
}

// ---------------------------------------------------------------------------
extern "C" void kernel_launch(void* const* d_in, const int* in_sizes, int n_in,
                              void* d_out, int out_size, void* d_ws, size_t ws_size,
                              hipStream_t stream) {
  (void)in_sizes; (void)n_in; (void)out_size;
  const float* query  = (const float*)d_in[0];
  const float* key_in = (const float*)d_in[1];
  const float* value  = (const float*)d_in[2];
  const float* Wq = (const float*)d_in[3];
  const float* bq = (const float*)d_in[4];
  const float* Wk = (const float*)d_in[5];
  const float* bk = (const float*)d_in[6];
  const float* Wv = (const float*)d_in[7];
  const float* bv = (const float*)d_in[8];
  const float* Wo = (const float*)d_in[9];
  const float* bo = (const float*)d_in[10];

  char* ws = (char*)d_ws;
  const size_t WSZ = 2097152;     // 1024*1024*2
  const size_t ASZ = 33554432;    // 16384*1024*2
  u16* WtQ = (u16*)(ws + 0 * WSZ);
  u16* WtK = (u16*)(ws + 1 * WSZ);
  u16* WtV = (u16*)(ws + 2 * WSZ);
  u16* WtO = (u16*)(ws + 3 * WSZ);
  u16* T   = (u16*)(ws + 4 * WSZ);                 // shared bf16 input temp
  u16* qb  = (u16*)(ws + 4 * WSZ + 1 * ASZ);
  u16* kb  = (u16*)(ws + 4 * WSZ + 2 * ASZ);
  u16* vb  = (u16*)(ws + 4 * WSZ + 3 * ASZ);
  u16* ao  = (u16*)(ws + 4 * WSZ + 4 * ASZ);
  if (ws_size < (size_t)168034304) return;

  wcvt_kernel<<<256, 256, 0, stream>>>(Wq, WtQ);
  wcvt_kernel<<<256, 256, 0, stream>>>(Wk, WtK);
  wcvt_kernel<<<256, 256, 0, stream>>>(Wv, WtV);
  wcvt_kernel<<<256, 256, 0, stream>>>(Wo, WtO);

  const int n8 = 16384 * 1024 / 8;
  cvt_kernel<<<2048, 256, 0, stream>>>(query, T, n8);
  gemm_bt<0><<<1024, 256, 0, stream>>>(T, WtQ, bq, qb, 16384, 1024, 1024);
  cvt_kernel<<<2048, 256, 0, stream>>>(key_in, T, n8);
  gemm_bt<0><<<1024, 256, 0, stream>>>(T, WtK, bk, kb, 16384, 1024, 1024);
  cvt_kernel<<<2048, 256, 0, stream>>>(value, T, n8);
  gemm_bt<0><<<1024, 256, 0, stream>>>(T, WtV, bv, vb, 16384, 1024, 1024);

  attn_kernel<<<2048, 128, 0, stream>>>(qb, kb, vb, ao);

  gemm_bt<1><<<776, 256, 0, stream>>>(ao, WtO, bo, (float*)d_out, 12416, 1024, 1024);
}

// Round 3
// 268.039 us; speedup vs baseline: 2.7362x; 1.2930x over previous
//
#include <hip/hip_runtime.h>
#include <hip/hip_bf16.h>

typedef __bf16 bf16x8 __attribute__((ext_vector_type(8)));
typedef float f32x4 __attribute__((ext_vector_type(4)));
typedef unsigned short u16;

#define DEV __device__ __forceinline__
#define MFMA16 __builtin_amdgcn_mfma_f32_16x16x32_bf16

DEV u16 f2b(float f) {
  __hip_bfloat16 h = __float2bfloat16(f);
  return __builtin_bit_cast(u16, h);
}

DEV void gl_lds16(const u16* g, u16* l) {
  __builtin_amdgcn_global_load_lds(
      (const __attribute__((address_space(1))) void*)g,
      (__attribute__((address_space(3))) void*)l, 16, 0, 0);
}

// ---------------------------------------------------------------------------
// f32 -> bf16 elementwise convert
// ---------------------------------------------------------------------------
__global__ __launch_bounds__(256) void cvt_kernel(const float* __restrict__ in,
                                                  u16* __restrict__ out, int n8) {
  const int stride = gridDim.x * 256;
  for (int i = blockIdx.x * 256 + threadIdx.x; i < n8; i += stride) {
    const float4 a = *reinterpret_cast<const float4*>(in + (size_t)i * 8);
    const float4 b = *reinterpret_cast<const float4*>(in + (size_t)i * 8 + 4);
    union { u16 s[8]; uint4 u; } o;
    o.s[0] = f2b(a.x); o.s[1] = f2b(a.y); o.s[2] = f2b(a.z); o.s[3] = f2b(a.w);
    o.s[4] = f2b(b.x); o.s[5] = f2b(b.y); o.s[6] = f2b(b.z); o.s[7] = f2b(b.w);
    *reinterpret_cast<uint4*>(out + (size_t)i * 8) = o.u;
  }
}

// ---------------------------------------------------------------------------
// Weight convert+transpose: W (1024x1024 f32, row=k) -> Wt (1024x1024 bf16, row=n)
// ---------------------------------------------------------------------------
__global__ __launch_bounds__(256) void wcvt_kernel(const float* __restrict__ W,
                                                   u16* __restrict__ Wt) {
  __shared__ u16 ls[64 * 80];
  const int bn = (blockIdx.x & 15) << 6;
  const int bk = (blockIdx.x >> 4) << 6;
  const int t = threadIdx.x;
#pragma unroll
  for (int rr = 0; rr < 4; ++rr) {
    const int r = (t >> 4) + (rr << 4);
    const int cc = (t & 15) << 2;
    const float4 v = *reinterpret_cast<const float4*>(&W[(size_t)(bk + r) * 1024 + bn + cc]);
    ls[(cc + 0) * 80 + r] = f2b(v.x);
    ls[(cc + 1) * 80 + r] = f2b(v.y);
    ls[(cc + 2) * 80 + r] = f2b(v.z);
    ls[(cc + 3) * 80 + r] = f2b(v.w);
  }
  __syncthreads();
#pragma unroll
  for (int it = 0; it < 2; ++it) {
    const int idx = t + (it << 8);
    const int n = idx >> 3, c8 = idx & 7;
    const uint4 o = *reinterpret_cast<const uint4*>(&ls[n * 80 + (c8 << 3)]);
    *reinterpret_cast<uint4*>(&Wt[(size_t)(bn + n) * 1024 + bk + (c8 << 3)]) = o;
  }
}

// ---------------------------------------------------------------------------
// 256x256-tile 8-wave 4-phase/K-tile GEMM (m201-style).
// C(M,N) = A(M,K) @ Bt(N,K)^T + bias.  BK=64, LDS 128KB double-buffered.
// T2 swizzle: linear global_load_lds dest + pre-swizzled global src; frag
// ds_read_b128 at slot (kk*4+g)^(row&7).  Counted vmcnt(4) per K-tile.
// ---------------------------------------------------------------------------
#define MF_CL(PR, PC, AF, BF)                                                  \
  asm volatile("s_waitcnt lgkmcnt(0)" ::: "memory");                           \
  __builtin_amdgcn_sched_barrier(0);                                           \
  __builtin_amdgcn_s_setprio(1);                                               \
  _Pragma("unroll") for (int i = 0; i < 4; ++i)                                \
  _Pragma("unroll") for (int j = 0; j < 2; ++j) {                              \
    acc[(PR)*4 + i][(PC)*2 + j] =                                              \
        MFMA16(AF[i][0], BF[j][0], acc[(PR)*4 + i][(PC)*2 + j], 0, 0, 0);      \
    acc[(PR)*4 + i][(PC)*2 + j] =                                              \
        MFMA16(AF[i][1], BF[j][1], acc[(PR)*4 + i][(PC)*2 + j], 0, 0, 0);      \
  }                                                                            \
  __builtin_amdgcn_s_setprio(0);

#define BAR()  __builtin_amdgcn_s_barrier()
#define SBAR() __builtin_amdgcn_sched_barrier(0)

template <int OUT_F32>
__global__ __launch_bounds__(512, 2) void gemm256(
    const u16* __restrict__ A, const u16* __restrict__ Bt,
    const float* __restrict__ bias, void* __restrict__ Cp,
    const int M, const int N, const int K) {
  __shared__ u16 smem[65536];                       // 128 KiB
  u16* const AbA[2] = {smem, smem + 16384};         // 256x64 each
  u16* const BbA[2] = {smem + 32768, smem + 49152};
  const int NT = K >> 6;
  const int tid = threadIdx.x;
  const int lane = tid & 63;
  const int w = tid >> 6;
  const int c = lane & 15, g = lane >> 4;

  // bijective XCD-chunked swizzle (works for any gridDim)
  const int nwg = (int)gridDim.x;
  const int q = nwg >> 3, r = nwg & 7;
  const int xcd = (int)blockIdx.x & 7, loc = (int)blockIdx.x >> 3;
  const int bid = (xcd < r ? xcd * (q + 1) : r * (q + 1) + (xcd - r) * q) + loc;
  const int ntN = N >> 8;
  const int bm = bid / ntN, bn = bid - bm * ntN;
  const int m0 = bm << 8, n0 = bn << 8;

  const int rl = lane >> 3;                       // staging row-in-8
  const int swc = ((lane & 7) ^ rl) << 3;         // pre-swizzled source col (elems)
  const int wrow = w << 3;                        // wave's 8-row chunk in a 64-row issue
  const int wm = (w >> 2) << 7, wn = (w & 3) << 6;

  // stage one 64-row contiguous chunk (2 global_load_lds... no: 1 per thread)
  auto stA64 = [&](int t, int row0) {
    u16* b = AbA[t & 1];
    gl_lds16(A + (size_t)(m0 + row0 + wrow + rl) * K + (t << 6) + swc,
             &b[(row0 + wrow) << 6]);
  };
  auto stB32 = [&](int t, int ra, int rb) {       // two 32-row chunks
    u16* b = BbA[t & 1];
    const int r0 = (w < 4) ? (ra + (w << 3)) : (rb + ((w - 4) << 3));
    gl_lds16(Bt + (size_t)(n0 + r0 + rl) * K + (t << 6) + swc, &b[r0 << 6]);
  };

  const int sK0 = (g ^ (c & 7)) << 3;             // swizzled slot*8, kk=0
  const int sK1 = ((4 + g) ^ (c & 7)) << 3;       // kk=1
  auto rdA = [&](u16* Ac, int poff, bf16x8 (&dst)[4][2]) {
#pragma unroll
    for (int mi = 0; mi < 4; ++mi) {
      const int ro = (wm + poff + (mi << 4) + c) << 6;
      dst[mi][0] = *reinterpret_cast<const bf16x8*>(&Ac[ro + sK0]);
      dst[mi][1] = *reinterpret_cast<const bf16x8*>(&Ac[ro + sK1]);
    }
  };
  auto rdB = [&](u16* Bc, int poff, bf16x8 (&dst)[2][2]) {
#pragma unroll
    for (int ni = 0; ni < 2; ++ni) {
      const int ro = (wn + poff + (ni << 4) + c) << 6;
      dst[ni][0] = *reinterpret_cast<const bf16x8*>(&Bc[ro + sK0]);
      dst[ni][1] = *reinterpret_cast<const bf16x8*>(&Bc[ro + sK1]);
    }
  };

  f32x4 acc[8][4];
#pragma unroll
  for (int mi = 0; mi < 8; ++mi)
#pragma unroll
    for (int ni = 0; ni < 4; ++ni) acc[mi][ni] = f32x4{0.f, 0.f, 0.f, 0.f};

  // ---- prologue: K-tile 0 fully + A0/B0 of K-tile 1 in flight ----
  stA64(0, 0); stA64(0, 128); stB32(0, 0, 64); stB32(0, 128, 192);   // A0(0), B0(0)
  stA64(0, 64); stA64(0, 192); stB32(0, 32, 96); stB32(0, 160, 224); // A1(0), B1(0)
  if (NT > 1) { stA64(1, 0); stA64(1, 128); stB32(1, 0, 64); stB32(1, 128, 192); }
  SBAR();
  asm volatile("s_waitcnt vmcnt(4)" ::: "memory");
  SBAR();
  BAR();

  bf16x8 af[4][2], b0f[2][2], b1f[2][2];
  for (int t2 = 0; t2 < NT; t2 += 2) {
#pragma unroll
    for (int half = 0; half < 2; ++half) {
      const int t = t2 + half;
      u16* const Ac = AbA[half];
      u16* const Bc = BbA[half];
      const int tn = t + 1, tn2 = t + 2;
      // --- ph0: read A-sub0 + B-sub0; stage A1(t+1)
      rdA(Ac, 0, af);
      rdB(Bc, 0, b0f);
      if (tn < NT) { stA64(tn, 64); stA64(tn, 192); }
      BAR();
      MF_CL(0, 0, af, b0f);
      BAR(); SBAR();
      // --- ph1: read B-sub1; stage B1(t+1)
      rdB(Bc, 32, b1f);
      if (tn < NT) { stB32(tn, 32, 96); stB32(tn, 160, 224); }
      BAR();
      MF_CL(0, 1, af, b1f);
      BAR(); SBAR();
      // --- ph2: read A-sub1; stage A0(t+2) (dest rows freed after ph1)
      rdA(Ac, 64, af);
      if (tn2 < NT) { stA64(tn2, 0); stA64(tn2, 128); }
      BAR();
      MF_CL(1, 0, af, b0f);
      BAR(); SBAR();
      // --- ph3: stage B0(t+2) (dest rows freed after ph2); boundary vmcnt
      if (tn2 < NT) { stB32(tn2, 0, 64); stB32(tn2, 128, 192); }
      BAR();
      MF_CL(1, 1, af, b1f);
      if (tn2 < NT) {
        asm volatile("s_waitcnt vmcnt(4)" ::: "memory");
      } else {
        asm volatile("s_waitcnt vmcnt(0)" ::: "memory");
      }
      SBAR();
      BAR(); SBAR();
    }
  }

  // ---- epilogue ----
  float bv[4];
#pragma unroll
  for (int ni = 0; ni < 4; ++ni) bv[ni] = bias[n0 + wn + (ni << 4) + c];

  if (!OUT_F32) {
    u16* Cb = (u16*)Cp;
#pragma unroll
    for (int mi = 0; mi < 8; ++mi)
#pragma unroll
      for (int ni = 0; ni < 4; ++ni)
#pragma unroll
        for (int rr = 0; rr < 4; ++rr)
          smem[(wm + (mi << 4) + (g << 2) + rr) * 256 + wn + (ni << 4) + c] =
              f2b(acc[mi][ni][rr] + bv[ni]);
    __syncthreads();
#pragma unroll
    for (int i = 0; i < 16; ++i) {
      const int idx = (i << 9) + tid;
      const int row = idx >> 5, sl = idx & 31;
      if (m0 + row < M)
        *reinterpret_cast<uint4*>(&Cb[(size_t)(m0 + row) * N + n0 + (sl << 3)]) =
            *reinterpret_cast<const uint4*>(&smem[row * 256 + (sl << 3)]);
    }
  } else {
    float* Cf = (float*)Cp;
    float* fs = (float*)smem;                     // 128 rows x 256 f32 per half
#pragma unroll
    for (int hh = 0; hh < 2; ++hh) {
      __syncthreads();
      if ((w >> 2) == hh) {
#pragma unroll
        for (int mi = 0; mi < 8; ++mi)
#pragma unroll
          for (int ni = 0; ni < 4; ++ni)
#pragma unroll
            for (int rr = 0; rr < 4; ++rr)
              fs[((mi << 4) + (g << 2) + rr) * 256 + wn + (ni << 4) + c] =
                  acc[mi][ni][rr] + bv[ni];
      }
      __syncthreads();
#pragma unroll
      for (int i = 0; i < 16; ++i) {
        const int idx = (i << 9) + tid;
        const int row = idx >> 6, sl = idx & 63;
        if (m0 + (hh << 7) + row < M)
          *reinterpret_cast<float4*>(&Cf[(size_t)(m0 + (hh << 7) + row) * N + n0 + (sl << 2)]) =
              *reinterpret_cast<const float4*>(&fs[row * 256 + (sl << 2)]);
      }
    }
  }
}

// ---------------------------------------------------------------------------
// Streaming attention (unchanged from round 2).
// ---------------------------------------------------------------------------
#define VT_STR 200
#define PS_STR 168

template <int NKT>
DEV void attn_process(const u16* __restrict__ Qg, const u16* __restrict__ Kg,
                      u16* __restrict__ Og, const u16* Vt, u16* Pw,
                      int b, int h, int qpos0, int kpos0, int obase, int nqt,
                      int wv, int lane) {
  const int c = lane & 15, g = lane >> 4;
  constexpr float SC = 0.18033688f;  // (1/sqrt(64)) * log2(e)
  for (int qt = wv; qt < nqt; qt += 2) {
    bf16x8 aq[2];
#pragma unroll
    for (int kk = 0; kk < 2; ++kk)
      aq[kk] = *reinterpret_cast<const bf16x8*>(
          Qg + ((size_t)(b * 4096 + qpos0 + (qt << 4) + c)) * 1024 + h * 64 + (kk << 5) + (g << 3));

    f32x4 sacc[NKT];
#pragma unroll
    for (int i = 0; i < NKT; ++i) sacc[i] = f32x4{0.f, 0.f, 0.f, 0.f};
#pragma unroll
    for (int kt = 0; kt < NKT; ++kt) {
#pragma unroll
      for (int kk = 0; kk < 2; ++kk) {
        const bf16x8 bk = *reinterpret_cast<const bf16x8*>(
            Kg + ((size_t)(b * 4096 + kpos0 + (kt << 4) + c)) * 1024 + h * 64 + (kk << 5) + (g << 3));
        sacc[kt] = MFMA16(aq[kk], bk, sacc[kt], 0, 0, 0);
      }
    }

    float m[4], sum[4], rs[4];
#pragma unroll
    for (int r = 0; r < 4; ++r) m[r] = -1e30f;
#pragma unroll
    for (int kt = 0; kt < NKT; ++kt)
#pragma unroll
      for (int r = 0; r < 4; ++r) m[r] = fmaxf(m[r], sacc[kt][r]);
#pragma unroll
    for (int msk = 1; msk < 16; msk <<= 1)
#pragma unroll
      for (int r = 0; r < 4; ++r) m[r] = fmaxf(m[r], __shfl_xor(m[r], msk, 64));
#pragma unroll
    for (int r = 0; r < 4; ++r) { m[r] *= SC; sum[r] = 0.f; }
#pragma unroll
    for (int kt = 0; kt < NKT; ++kt)
#pragma unroll
      for (int r = 0; r < 4; ++r) {
        const float p = exp2f(sacc[kt][r] * SC - m[r]);
        sum[r] += p;
        Pw[((g << 2) + r) * PS_STR + (kt << 4) + c] = f2b(p);
      }
#pragma unroll
    for (int msk = 1; msk < 16; msk <<= 1)
#pragma unroll
      for (int r = 0; r < 4; ++r) sum[r] += __shfl_xor(sum[r], msk, 64);
#pragma unroll
    for (int r = 0; r < 4; ++r) rs[r] = 1.f / sum[r];

    asm volatile("s_waitcnt lgkmcnt(0)" ::: "memory");
    __builtin_amdgcn_sched_barrier(0);

    f32x4 oacc[4];
#pragma unroll
    for (int nd = 0; nd < 4; ++nd) oacc[nd] = f32x4{0.f, 0.f, 0.f, 0.f};
#pragma unroll
    for (int u = 0; u < NKT / 2; ++u) {
      const bf16x8 pa = *reinterpret_cast<const bf16x8*>(&Pw[c * PS_STR + (u << 5) + (g << 3)]);
#pragma unroll
      for (int nd = 0; nd < 4; ++nd) {
        const int d = (nd << 4) + c;
        const int a = (u << 2) + g;
        const int us = (a & 24) | ((a ^ (d >> 3)) & 7);
        const bf16x8 vbf = *reinterpret_cast<const bf16x8*>(&Vt[d * VT_STR + (us << 3)]);
        oacc[nd] = MFMA16(pa, vbf, oacc[nd], 0, 0, 0);
      }
    }

    const int orow0 = b * 3104 + obase + (qt << 4) + (g << 2);
#pragma unroll
    for (int nd = 0; nd < 4; ++nd)
#pragma unroll
      for (int r = 0; r < 4; ++r)
        Og[(size_t)(orow0 + r) * 1024 + h * 64 + (nd << 4) + c] = f2b(oacc[nd][r] * rs[r]);
  }
}

__global__ __launch_bounds__(128) void attn_kernel(
    const u16* __restrict__ Qg, const u16* __restrict__ Kg,
    const u16* __restrict__ Vg, u16* __restrict__ Og) {
  __shared__ u16 Vt[64 * VT_STR];
  __shared__ u16 Ps[2 * 16 * PS_STR];
  const int bid = blockIdx.x;
  const int b = bid >> 9;
  const int ch = (bid >> 4) & 31;
  const int h = bid & 15;
  const int t = threadIdx.x, wv = t >> 6, lane = t & 63;
  int qpos0, kpos0, obase, nk;
  if (ch == 0) { qpos0 = 0; kpos0 = 0; obase = 0; nk = 128; }
  else { qpos0 = (ch << 7) + 32; kpos0 = (ch << 7) - 32; obase = 128 + (ch - 1) * 96; nk = 160; }

  const size_t vbase = ((size_t)(b * 4096 + kpos0)) * 1024 + h * 64;
  for (int ch8 = t; ch8 < nk * 8; ch8 += 128) {
    const int k = ch8 >> 3, c8 = ch8 & 7;
    const uint4 v = *reinterpret_cast<const uint4*>(Vg + vbase + (size_t)k * 1024 + (c8 << 3));
    const unsigned vv[4] = {v.x, v.y, v.z, v.w};
    const int k8 = k >> 3;
    const int us = (k8 & 24) | ((k8 ^ c8) & 7);
    const int base = (us << 3) + (k & 7);
#pragma unroll
    for (int j = 0; j < 8; ++j) {
      const u16 e = (u16)(vv[j >> 1] >> ((j & 1) << 4));
      Vt[((c8 << 3) + j) * VT_STR + base] = e;
    }
  }
  __syncthreads();

  u16* Pw = Ps + wv * (16 * PS_STR);
  if (ch == 0)
    attn_process<8>(Qg, Kg, Og, Vt, Pw, b, h, qpos0, kpos0, obase, 8, wv, lane);
  else
    attn_process<10>(Qg, Kg, Og, Vt, Pw, b, h, qpos0, kpos0, obase, 6, wv, lane);
}

// ---------------------------------------------------------------------------
extern "C" void kernel_launch(void* const* d_in, const int* in_sizes, int n_in,
                              void* d_out, int out_size, void* d_ws, size_t ws_size,
                              hipStream_t stream) {
  (void)in_sizes; (void)n_in; (void)out_size;
  const float* query  = (const float*)d_in[0];
  const float* key_in = (const float*)d_in[1];
  const float* value  = (const float*)d_in[2];
  const float* Wq = (const float*)d_in[3];
  const float* bq = (const float*)d_in[4];
  const float* Wk = (const float*)d_in[5];
  const float* bk = (const float*)d_in[6];
  const float* Wv = (const float*)d_in[7];
  const float* bv = (const float*)d_in[8];
  const float* Wo = (const float*)d_in[9];
  const float* bo = (const float*)d_in[10];

  char* ws = (char*)d_ws;
  const size_t WSZ = 2097152;     // 1024*1024*2
  const size_t ASZ = 33554432;    // 16384*1024*2
  u16* WtQ = (u16*)(ws + 0 * WSZ);
  u16* WtK = (u16*)(ws + 1 * WSZ);
  u16* WtV = (u16*)(ws + 2 * WSZ);
  u16* WtO = (u16*)(ws + 3 * WSZ);
  u16* T   = (u16*)(ws + 4 * WSZ);                // bf16 input temp; later aliased by ao
  u16* ao  = T;                                   // attn out (12544 rows padded, 24.5MB < 32MB)
  u16* qb  = (u16*)(ws + 4 * WSZ + 1 * ASZ);
  u16* kb  = (u16*)(ws + 4 * WSZ + 2 * ASZ);
  u16* vb  = (u16*)(ws + 4 * WSZ + 3 * ASZ);
  if (ws_size < (size_t)142606336) return;

  wcvt_kernel<<<256, 256, 0, stream>>>(Wq, WtQ);
  wcvt_kernel<<<256, 256, 0, stream>>>(Wk, WtK);
  wcvt_kernel<<<256, 256, 0, stream>>>(Wv, WtV);
  wcvt_kernel<<<256, 256, 0, stream>>>(Wo, WtO);

  const int n8 = 16384 * 1024 / 8;
  cvt_kernel<<<2048, 256, 0, stream>>>(query, T, n8);
  gemm256<0><<<256, 512, 0, stream>>>(T, WtQ, bq, qb, 16384, 1024, 1024);
  cvt_kernel<<<2048, 256, 0, stream>>>(key_in, T, n8);
  gemm256<0><<<256, 512, 0, stream>>>(T, WtK, bk, kb, 16384, 1024, 1024);
  cvt_kernel<<<2048, 256, 0, stream>>>(value, T, n8);
  gemm256<0><<<256, 512, 0, stream>>>(T, WtV, bv, vb, 16384, 1024, 1024);

  attn_kernel<<<2048, 128, 0, stream>>>(qb, kb, vb, ao);

  gemm256<1><<<196, 512, 0, stream>>>(ao, WtO, bo, (float*)d_out, 12416, 1024, 1024);
}